// Round 8
// baseline (925.642 us; speedup 1.0000x reference)
//
#include <hip/hip_runtime.h>
#include <math.h>

// SparseCoding, round 8.
// Structural rewrite vs R7 (343 us): ownership-aligned coef -> ONE barrier/iter.
//  - lane kg of wave ks owns coef (row kg>>3, cols 32ks+4(kg&7)..+3): the GEMM
//    broadcast coef[b][32ks+4m+u] is lane (8b+m)'s cf[u] REGISTER of the same
//    wave -> readlane from registers. No coef in LDS at all, no TOP barrier.
//  - only cross-wave flow: pacc -> a4 via parity double-buffered s_part (WAR-safe
//    across the single barrier).
//  - loss: post-barrier qc/rr over owned coefs, intra-wave shfl, then per-wave
//    lane0 fp64 global atomicAdd + RELEASE arrival (32 arrivals per window/iter).
//    tid64 consumes iter-(it-1) totals at loop top (hidden by partner wave).
#define NB     256
#define NF     128
#define FT     1024
#define NW     63
#define TORIG  256
#define MAXIT  48
#define RPB    8
#define NBLK   4
#define NARR   (8 * NBLK)    // arrivals per window per iter (8 waves x 4 blocks)
#define GRID   256           // XCD-swizzled; 4 blocks decode w==63: gram+exit

__device__ __forceinline__ float rl(float v, int lane) {
    return __uint_as_float((unsigned)__builtin_amdgcn_readlane((int)__float_as_uint(v), lane));
}

__global__ __launch_bounds__(512, 2) void window_kernel(
    const float* __restrict__ spec,
    const float* __restrict__ basis,
    float* __restrict__ G,               // ws: 256x256
    const int* __restrict__ p_niter,
    const int* __restrict__ p_pad,
    const int* __restrict__ p_stride,
    double* __restrict__ sxbuf,          // [NW][NBLK]
    double* __restrict__ gq,             // [MAXIT][NW] atomic Q accumulators (memset 0)
    double* __restrict__ gr_,            // [MAXIT][NW] atomic R accumulators (memset 0)
    unsigned int* __restrict__ gcnt,     // [MAXIT*NW] arrivals + [MAXIT*NW]=gbar (memset 0)
    float* __restrict__ out)             // (32,256,63)
{
    __shared__ float  s_p0[RPB * RPB * 256];   // 64 KB parity-0 exchange
    __shared__ float  s_p1[RPB * RPB * 256];   // 64 KB parity-1; head doubles as s_xn
    __shared__ float  s_gred[2][NB];
    __shared__ float  s_mn[RPB], s_rng[RPB];
    __shared__ double s_dred[8];
    __shared__ int    s_stop[2];
    float* const s_xn = s_p1;                  // 32 KB of parity-1, setup only

    const int bid = blockIdx.x;
    const int yy  = bid >> 3;
    const int q   = yy & 3;
    const int w   = (bid & 7) + 8 * (yy >> 2);   // window; 4 blocks/window share XCD
    const int tid = threadIdx.x;
    const int ks  = tid >> 6;                    // wave: K-slice [32ks,32ks+32)
    const int kg  = tid & 63;
    const int r   = kg >> 3;                     // owned local row
    const int c0  = 32 * ks + 4 * (kg & 7);      // owned cols c0..c0+3
    const int n_iter = p_niter[0];
    const int t0     = w * p_stride[0] - p_pad[0];
    unsigned int* gbar = gcnt + MAXIT * NW;

    // ================= fused Gram: block bid computes G row bid ==================
    {
        const int c = tid & 255, jh = tid >> 8;
        float acc = 0.f;
        const float* bp = basis + (size_t)(jh * 512) * NB;
        #pragma unroll 16
        for (int j = 0; j < 512; ++j)
            acc = fmaf(bp[j * NB + bid], bp[j * NB + c], acc);
        s_gred[jh][c] = acc;
        __syncthreads();
        if (jh == 0) G[(size_t)bid * NB + c] = s_gred[0][c] + s_gred[1][c];
    }
    __threadfence();
    __syncthreads();
    if (tid == 0) atomicAdd(gbar, 1u);
    if (w >= NW) return;

    // ================= stage raw window, min/max, normalize ======================
    #pragma unroll
    for (int i = 0; i < 16; ++i) {
        const int e = i * 512 + tid;
        const int b = e >> 10, jj = e & 1023;
        const int f = jj >> 3, t = jj & 7, tq = t0 + t;
        s_xn[b * FT + jj] = (tq >= 0 && tq < TORIG)
            ? spec[((size_t)(q * RPB + b) * NF + f) * TORIG + tq] : 0.f;
    }
    __syncthreads();
    {   // wave ks scans row ks
        float mn = __builtin_inff(), mx = -__builtin_inff();
        #pragma unroll
        for (int i = 0; i < 16; ++i) {
            const float v = s_xn[ks * FT + i * 64 + kg];
            mn = fminf(mn, v); mx = fmaxf(mx, v);
        }
        #pragma unroll
        for (int off = 32; off; off >>= 1) {
            mn = fminf(mn, __shfl_down(mn, off));
            mx = fmaxf(mx, __shfl_down(mx, off));
        }
        if (kg == 0) { s_mn[ks] = mn; s_rng[ks] = mx - mn; }
    }
    __syncthreads();
    double sx2p = 0.0;
    #pragma unroll
    for (int i = 0; i < 16; ++i) {
        const int e = i * 512 + tid;
        const int b = e >> 10, jj = e & 1023;
        const float v = (s_xn[b * FT + jj] - s_mn[b]) / s_rng[b];
        s_xn[b * FT + jj] = v;
        sx2p += (double)v * (double)v;
    }
    #pragma unroll
    for (int off = 32; off; off >>= 1) sx2p += __shfl_down(sx2p, off);
    if (kg == 0) s_dred[ks] = sx2p;
    __syncthreads();
    if (tid == 0) {
        double s = 0.0;
        #pragma unroll
        for (int i = 0; i < 8; ++i) s += s_dred[i];
        sxbuf[w * NBLK + q] = s;     // released by this thread's it=0 RELEASE arrival
    }

    // ================= xB = xnorm @ basis (K-split partials into s_p0) ===========
    float xbp[RPB][4];
    #pragma unroll
    for (int b = 0; b < RPB; ++b)
        #pragma unroll
        for (int j = 0; j < 4; ++j) xbp[b][j] = 0.f;
    for (int i0 = 0; i0 < 128; i0 += 4) {
        const int jj = ks * 128 + i0;
        float4 bv[4];
        #pragma unroll
        for (int t = 0; t < 4; ++t)
            bv[t] = *(const float4*)(basis + (size_t)(jj + t) * NB + 4 * kg);
        #pragma unroll
        for (int b = 0; b < RPB; ++b) {
            const float4 x4 = *(const float4*)&s_xn[b * FT + jj];
            xbp[b][0] = fmaf(x4.x, bv[0].x, fmaf(x4.y, bv[1].x, fmaf(x4.z, bv[2].x, fmaf(x4.w, bv[3].x, xbp[b][0]))));
            xbp[b][1] = fmaf(x4.x, bv[0].y, fmaf(x4.y, bv[1].y, fmaf(x4.z, bv[2].y, fmaf(x4.w, bv[3].y, xbp[b][1]))));
            xbp[b][2] = fmaf(x4.x, bv[0].z, fmaf(x4.y, bv[1].z, fmaf(x4.z, bv[2].z, fmaf(x4.w, bv[3].z, xbp[b][2]))));
            xbp[b][3] = fmaf(x4.x, bv[0].w, fmaf(x4.y, bv[1].w, fmaf(x4.z, bv[2].w, fmaf(x4.w, bv[3].w, xbp[b][3]))));
        }
    }
    __syncthreads();               // s_xn reads done before s_p0 overwrite is safe anyway
    #pragma unroll
    for (int b = 0; b < RPB; ++b)
        *(float4*)&s_p0[(ks * RPB + b) * 256 + 4 * kg] =
            make_float4(xbp[b][0], xbp[b][1], xbp[b][2], xbp[b][3]);
    __syncthreads();
    // gather xB at OWNED coords (row r, cols c0..c0+3)
    float xB[4] = {0.f, 0.f, 0.f, 0.f};
    #pragma unroll
    for (int k2 = 0; k2 < 8; ++k2) {
        const float4 p4 = *(const float4*)&s_p0[(k2 * RPB + r) * 256 + c0];
        xB[0] += p4.x; xB[1] += p4.y; xB[2] += p4.z; xB[3] += p4.w;
    }

    // ================= wait for G, load register fragment ========================
    if (tid == 0) {
        while (__hip_atomic_load(gbar, __ATOMIC_ACQUIRE, __HIP_MEMORY_SCOPE_AGENT) < (unsigned)GRID)
            __builtin_amdgcn_s_sleep(1);
    }
    __syncthreads();               // also separates xB gather (s_p0 read) from iter0 write
    float4 g[32];
    #pragma unroll
    for (int kl = 0; kl < 32; ++kl)
        g[kl] = *(const float4*)(G + (size_t)(32 * ks + kl) * NB + 4 * kg);

    // ================= init owned coef / Adam state ==============================
    const float C0 = 0.5f / 256.f;
    float cf[4] = {C0, C0, C0, C0}, m_[4] = {0, 0, 0, 0}, v_[4] = {0, 0, 0, 0};
    if (tid == 64) { s_stop[0] = 0; s_stop[1] = 0; }
    float b1p = 1.f, b2p = 1.f;
    float old_loss = 1e-10f;      // tid64 only
    double sxtot = 0.0;           // tid64 only
    const float c1 = 2.f / 32768.f, c2 = 0.2f / 8192.f;

    for (int it = 0; it < n_iter; ++it) {
        const int p = it & 1;
        float* const sp = p ? s_p1 : s_p0;

        // ---- tid64: consume iter-(it-1) decision (posted mid-body last iter) ----
        if (tid == 64 && it > 0) {
            while (__hip_atomic_load(&gcnt[(it - 1) * NW + w], __ATOMIC_ACQUIRE,
                                     __HIP_MEMORY_SCOPE_AGENT) < (unsigned)NARR)
                __builtin_amdgcn_s_sleep(1);
            const double Qt = gq[(it - 1) * NW + w];
            const double Rt = gr_[(it - 1) * NW + w];
            if (it == 1)
                sxtot = sxbuf[w * NBLK + 0] + sxbuf[w * NBLK + 1] +
                        sxbuf[w * NBLK + 2] + sxbuf[w * NBLK + 3];
            const float loss = (float)((Qt + sxtot) / 32768.0 + 0.2 * (Rt / 8192.0));
            const float stat = fabsf(old_loss - loss) / old_loss;
            old_loss = loss;
            s_stop[p] = (stat < 1e-3f) ? 1 : 0;
        }

        // ---- GEMM: broadcasts straight from own-wave registers ----
        float pacc[RPB][4];
        #pragma unroll
        for (int b = 0; b < RPB; ++b)
            #pragma unroll
            for (int j = 0; j < 4; ++j) pacc[b][j] = 0.f;
        #pragma unroll
        for (int m = 0; m < 8; ++m) {
            const float4 ga = g[4 * m + 0], gb = g[4 * m + 1];
            const float4 gc = g[4 * m + 2], gd = g[4 * m + 3];
            #pragma unroll
            for (int b = 0; b < RPB; ++b) {
                const int L = b * 8 + m;     // lane owning coef[b][32ks+4m..+3]
                const float cx = rl(cf[0], L), cy = rl(cf[1], L);
                const float cz = rl(cf[2], L), cw = rl(cf[3], L);
                pacc[b][0] = fmaf(cx, ga.x, fmaf(cy, gb.x, fmaf(cz, gc.x, fmaf(cw, gd.x, pacc[b][0]))));
                pacc[b][1] = fmaf(cx, ga.y, fmaf(cy, gb.y, fmaf(cz, gc.y, fmaf(cw, gd.y, pacc[b][1]))));
                pacc[b][2] = fmaf(cx, ga.z, fmaf(cy, gb.z, fmaf(cz, gc.z, fmaf(cw, gd.z, pacc[b][2]))));
                pacc[b][3] = fmaf(cx, ga.w, fmaf(cy, gb.w, fmaf(cz, gc.w, fmaf(cw, gd.w, pacc[b][3]))));
            }
        }
        // post K-slice partials (pacc dies here, before the barrier)
        #pragma unroll
        for (int b = 0; b < RPB; ++b)
            *(float4*)&sp[(ks * RPB + b) * 256 + 4 * kg] =
                make_float4(pacc[b][0], pacc[b][1], pacc[b][2], pacc[b][3]);

        __syncthreads();          // THE barrier: s_part[p] + s_stop[p] visible

        if (s_stop[p]) break;     // conv(it-1) gates update(it)

        // ---- K-reduce at owned coords ----
        float a4[4] = {0.f, 0.f, 0.f, 0.f};
        #pragma unroll
        for (int k2 = 0; k2 < 8; ++k2) {
            const float4 p4 = *(const float4*)&sp[(k2 * RPB + r) * 256 + c0];
            a4[0] += p4.x; a4[1] += p4.y; a4[2] += p4.z; a4[3] += p4.w;
        }

        // ---- loss partials over owned coefs (coverage exact: each output once) ----
        float qc = 0.f, rr = 0.f;
        #pragma unroll
        for (int j = 0; j < 4; ++j) {
            qc += cf[j] * (a4[j] - 2.f * xB[j]);
            rr += fabsf(cf[j]);
        }
        #pragma unroll
        for (int off = 32; off; off >>= 1) {
            qc += __shfl_down(qc, off);
            rr += __shfl_down(rr, off);
        }
        if (kg == 0) {            // per-wave fp64 atomic post + RELEASE arrival
            atomicAdd(&gq[it * NW + w], (double)qc);
            atomicAdd(&gr_[it * NW + w], (double)rr);
            __hip_atomic_fetch_add(&gcnt[it * NW + w], 1u,
                                   __ATOMIC_RELEASE, __HIP_MEMORY_SCOPE_AGENT);
        }

        // ---- Adam update on owned coefs (registers only) ----
        b1p *= 0.9f; b2p *= 0.999f;
        const float bc1 = 1.f - b1p, bc2 = 1.f - b2p;
        #pragma unroll
        for (int j = 0; j < 4; ++j) {
            const float c_ = cf[j];
            const float sgn = (c_ > 0.f) ? 1.f : ((c_ < 0.f) ? -1.f : 0.f);
            const float gg = c1 * (a4[j] - xB[j]) + c2 * sgn;
            m_[j] = 0.9f * m_[j] + 0.1f * gg;
            v_[j] = 0.999f * v_[j] + 0.001f * gg * gg;
            cf[j] = c_ - 1e-3f * (m_[j] / bc1) / (sqrtf(v_[j] / bc2) + 1e-8f);
        }
    }

    // ---- out[b][k][w]: owned (row q*8+r, cols c0..c0+3) ----
    #pragma unroll
    for (int j = 0; j < 4; ++j)
        out[((size_t)(q * RPB + r) * NB + c0 + j) * NW + w] = cf[j];
}

// ---------------------------------------------------------------------------
extern "C" void kernel_launch(void* const* d_in, const int* in_sizes, int n_in,
                              void* d_out, int out_size, void* d_ws, size_t ws_size,
                              hipStream_t stream)
{
    const float* spec   = (const float*)d_in[0];
    const float* basis  = (const float*)d_in[1];
    const int* p_niter  = (const int*)d_in[2];
    const int* p_pad    = (const int*)d_in[3];
    const int* p_stride = (const int*)d_in[4];
    float* out = (float*)d_out;

    char* ws = (char*)d_ws;
    float*        G     = (float*)ws;                         // 256 KB
    double*       sxbuf = (double*)(ws + 262144);             // 2016 B (pad to 4 KB)
    double*       gq    = (double*)(ws + 266240);             // 24192 B (pad 24576)
    double*       gr_   = (double*)(ws + 290816);             // 24192 B (pad 24576)
    unsigned int* gcnt  = (unsigned int*)(ws + 315392);       // (MAXIT*NW+1)*4 = 12100 B

    // zero the atomic accumulators + counters (gq, gr_, gcnt are contiguous)
    hipMemsetAsync(ws + 266240, 0, 24576 + 24576 + 12100 + 28, stream);
    window_kernel<<<dim3(GRID), dim3(512), 0, stream>>>(
        spec, basis, G, p_niter, p_pad, p_stride, sxbuf, gq, gr_, gcnt, out);
}

// Round 9
// 322.729 us; speedup vs baseline: 2.8682x; 2.8682x over previous
//
#include <hip/hip_runtime.h>
#include <math.h>

// SparseCoding, round 9.
// vs R8 (926 us): keep ownership-aligned GEMM (coef in registers, readlane
// broadcasts, ONE barrier/iter) but fix R8's two diagnosed regressions:
//  (1) loss sync: per-block last-man-out via LDS (plain s_red stores +
//      threadfence_block + LDS counter; 8th wave sums in fixed order) ->
//      4 global arrivals/window/iter (R7 level), not 32 serialized fp64 atomics.
//      tid64 consumes iter-(it-1) AFTER its GEMM, right before the barrier ->
//      ~one full iteration of slack (R8 had zero).
//  (2) LDS exchange XOR-swizzle: idx4(k2,cg,row)=k2*512+row*64+(cg^row);
//      writer (fixed row, lanes kg -> kg^row) and reader (permutation of a
//      contiguous 64-float4 block) are both conflict-minimal.
#define NB     256
#define NF     128
#define FT     1024
#define NW     63
#define TORIG  256
#define MAXIT  48
#define RPB    8
#define NBLK   4
#define GRID   256           // XCD-swizzled; 4 blocks decode w==63: gram+exit

__device__ __forceinline__ float rl(float v, int lane) {
    return __uint_as_float((unsigned)__builtin_amdgcn_readlane((int)__float_as_uint(v), lane));
}

// exchange layout (float4 index): k2*512 + row*64 + (cg ^ row), cg=colgroup 0..63
__device__ __forceinline__ int xidx(int k2, int cg, int row) {
    return (k2 * 512 + row * 64 + (cg ^ row)) * 4;
}

__global__ __launch_bounds__(512, 2) void window_kernel(
    const float* __restrict__ spec,
    const float* __restrict__ basis,
    float* __restrict__ G,               // ws: 256x256
    const int* __restrict__ p_niter,
    const int* __restrict__ p_pad,
    const int* __restrict__ p_stride,
    double* __restrict__ sxbuf,          // [NW][NBLK]
    double* __restrict__ gpart,          // [MAXIT][NW][NBLK][2]
    unsigned int* __restrict__ gcnt,     // [MAXIT*NW] arrivals + [MAXIT*NW]=gbar (memset 0)
    float* __restrict__ out)             // (32,256,63)
{
    __shared__ float  s_p0[RPB * 2048];        // 64 KB parity-0 exchange
    __shared__ float  s_p1[RPB * 2048];        // 64 KB parity-1; head doubles as s_xn
    __shared__ float  s_gred[2][NB];
    __shared__ float  s_mn[RPB], s_rng[RPB];
    __shared__ double s_dred[8];
    __shared__ float  s_redq[2][8], s_redr[2][8];
    __shared__ unsigned int s_wcnt[2];
    __shared__ int    s_stop[2];
    float* const s_xn = s_p1;                  // setup only

    const int bid = blockIdx.x;
    const int yy  = bid >> 3;
    const int q   = yy & 3;
    const int w   = (bid & 7) + 8 * (yy >> 2);   // 4 blocks/window share bid%8 (XCD)
    const int tid = threadIdx.x;
    const int ks  = tid >> 6;                    // wave: K-slice [32ks,32ks+32)
    const int kg  = tid & 63;
    const int r   = kg >> 3;                     // owned local row
    const int cgo = 8 * ks + (kg & 7);           // owned colgroup (cols 4cgo..4cgo+3)
    const int n_iter = p_niter[0];
    const int t0     = w * p_stride[0] - p_pad[0];
    unsigned int* gbar = gcnt + MAXIT * NW;

    // ================= fused Gram: block bid computes G row bid ==================
    {
        const int c = tid & 255, jh = tid >> 8;
        float acc = 0.f;
        const float* bp = basis + (size_t)(jh * 512) * NB;
        #pragma unroll 16
        for (int j = 0; j < 512; ++j)
            acc = fmaf(bp[j * NB + bid], bp[j * NB + c], acc);
        s_gred[jh][c] = acc;
        __syncthreads();
        if (jh == 0) G[(size_t)bid * NB + c] = s_gred[0][c] + s_gred[1][c];
    }
    __threadfence();
    __syncthreads();
    if (tid == 0) atomicAdd(gbar, 1u);
    if (w >= NW) return;

    // ================= stage raw window, min/max, normalize ======================
    #pragma unroll
    for (int i = 0; i < 16; ++i) {
        const int e = i * 512 + tid;
        const int b = e >> 10, jj = e & 1023;
        const int f = jj >> 3, t = jj & 7, tq = t0 + t;
        s_xn[b * FT + jj] = (tq >= 0 && tq < TORIG)
            ? spec[((size_t)(q * RPB + b) * NF + f) * TORIG + tq] : 0.f;
    }
    __syncthreads();
    {   // wave ks scans row ks
        float mn = __builtin_inff(), mx = -__builtin_inff();
        #pragma unroll
        for (int i = 0; i < 16; ++i) {
            const float v = s_xn[ks * FT + i * 64 + kg];
            mn = fminf(mn, v); mx = fmaxf(mx, v);
        }
        #pragma unroll
        for (int off = 32; off; off >>= 1) {
            mn = fminf(mn, __shfl_down(mn, off));
            mx = fmaxf(mx, __shfl_down(mx, off));
        }
        if (kg == 0) { s_mn[ks] = mn; s_rng[ks] = mx - mn; }
    }
    __syncthreads();
    double sx2p = 0.0;
    #pragma unroll
    for (int i = 0; i < 16; ++i) {
        const int e = i * 512 + tid;
        const int b = e >> 10, jj = e & 1023;
        const float v = (s_xn[b * FT + jj] - s_mn[b]) / s_rng[b];
        s_xn[b * FT + jj] = v;
        sx2p += (double)v * (double)v;
    }
    #pragma unroll
    for (int off = 32; off; off >>= 1) sx2p += __shfl_down(sx2p, off);
    if (kg == 0) s_dred[ks] = sx2p;
    __syncthreads();
    if (tid == 0) {
        double s = 0.0;
        #pragma unroll
        for (int i = 0; i < 8; ++i) s += s_dred[i];
        sxbuf[w * NBLK + q] = s;
        __threadfence();               // make sxbuf visible well before it==1 consume
    }

    // ================= xB = xnorm @ basis (K-split partials into s_p0) ===========
    float xbp[RPB][4];
    #pragma unroll
    for (int b = 0; b < RPB; ++b)
        #pragma unroll
        for (int j = 0; j < 4; ++j) xbp[b][j] = 0.f;
    for (int i0 = 0; i0 < 128; i0 += 4) {
        const int jj = ks * 128 + i0;
        float4 bv[4];
        #pragma unroll
        for (int t = 0; t < 4; ++t)
            bv[t] = *(const float4*)(basis + (size_t)(jj + t) * NB + 4 * kg);
        #pragma unroll
        for (int b = 0; b < RPB; ++b) {
            const float4 x4 = *(const float4*)&s_xn[b * FT + jj];
            xbp[b][0] = fmaf(x4.x, bv[0].x, fmaf(x4.y, bv[1].x, fmaf(x4.z, bv[2].x, fmaf(x4.w, bv[3].x, xbp[b][0]))));
            xbp[b][1] = fmaf(x4.x, bv[0].y, fmaf(x4.y, bv[1].y, fmaf(x4.z, bv[2].y, fmaf(x4.w, bv[3].y, xbp[b][1]))));
            xbp[b][2] = fmaf(x4.x, bv[0].z, fmaf(x4.y, bv[1].z, fmaf(x4.z, bv[2].z, fmaf(x4.w, bv[3].z, xbp[b][2]))));
            xbp[b][3] = fmaf(x4.x, bv[0].w, fmaf(x4.y, bv[1].w, fmaf(x4.z, bv[2].w, fmaf(x4.w, bv[3].w, xbp[b][3]))));
        }
    }
    __syncthreads();               // s_xn reads done
    #pragma unroll
    for (int b = 0; b < RPB; ++b)
        *(float4*)&s_p0[xidx(ks, kg, b)] =
            make_float4(xbp[b][0], xbp[b][1], xbp[b][2], xbp[b][3]);
    __syncthreads();
    float xB[4] = {0.f, 0.f, 0.f, 0.f};
    #pragma unroll
    for (int k2 = 0; k2 < 8; ++k2) {
        const float4 p4 = *(const float4*)&s_p0[xidx(k2, cgo, r)];
        xB[0] += p4.x; xB[1] += p4.y; xB[2] += p4.z; xB[3] += p4.w;
    }

    // ================= wait for G, load register fragment ========================
    if (tid == 0) {
        while (__hip_atomic_load(gbar, __ATOMIC_ACQUIRE, __HIP_MEMORY_SCOPE_AGENT) < (unsigned)GRID)
            __builtin_amdgcn_s_sleep(1);
    }
    if (tid == 64) { s_wcnt[0] = 0; s_wcnt[1] = 0; s_stop[0] = 0; s_stop[1] = 0; }
    __syncthreads();               // xB gather done; G ready; s_wcnt/s_stop init
    float4 g[32];
    #pragma unroll
    for (int kl = 0; kl < 32; ++kl)
        g[kl] = *(const float4*)(G + (size_t)(32 * ks + kl) * NB + 4 * kg);

    // ================= init owned coef / Adam ====================================
    const float C0 = 0.5f / 256.f;
    float cf[4] = {C0, C0, C0, C0}, m_[4] = {0, 0, 0, 0}, v_[4] = {0, 0, 0, 0};
    float b1p = 1.f, b2p = 1.f;
    float old_loss = 1e-10f;      // tid64 only
    double sxtot = 0.0;           // tid64 only
    const float c1 = 2.f / 32768.f, c2 = 0.2f / 8192.f;

    for (int it = 0; it < n_iter; ++it) {
        const int p = it & 1;
        float* const sp = p ? s_p1 : s_p0;

        // ---- GEMM: broadcasts straight from own-wave registers ----
        float pacc[RPB][4];
        #pragma unroll
        for (int b = 0; b < RPB; ++b)
            #pragma unroll
            for (int j = 0; j < 4; ++j) pacc[b][j] = 0.f;
        #pragma unroll
        for (int m = 0; m < 8; ++m) {
            const float4 ga = g[4 * m + 0], gb = g[4 * m + 1];
            const float4 gc = g[4 * m + 2], gd = g[4 * m + 3];
            #pragma unroll
            for (int b = 0; b < RPB; ++b) {
                const int L = b * 8 + m;     // lane owning coef[b][32ks+4m..+3]
                const float cx = rl(cf[0], L), cy = rl(cf[1], L);
                const float cz = rl(cf[2], L), cw = rl(cf[3], L);
                pacc[b][0] = fmaf(cx, ga.x, fmaf(cy, gb.x, fmaf(cz, gc.x, fmaf(cw, gd.x, pacc[b][0]))));
                pacc[b][1] = fmaf(cx, ga.y, fmaf(cy, gb.y, fmaf(cz, gc.y, fmaf(cw, gd.y, pacc[b][1]))));
                pacc[b][2] = fmaf(cx, ga.z, fmaf(cy, gb.z, fmaf(cz, gc.z, fmaf(cw, gd.z, pacc[b][2]))));
                pacc[b][3] = fmaf(cx, ga.w, fmaf(cy, gb.w, fmaf(cz, gc.w, fmaf(cw, gd.w, pacc[b][3]))));
            }
        }
        // post K-slice partials (pacc dies here, before the barrier)
        #pragma unroll
        for (int b = 0; b < RPB; ++b)
            *(float4*)&sp[xidx(ks, kg, b)] =
                make_float4(pacc[b][0], pacc[b][1], pacc[b][2], pacc[b][3]);

        // ---- tid64: consume iter-(it-1) decision LAST (max slack; posts happened
        //      shortly after the previous barrier in all sibling blocks) ----
        if (tid == 64 && it > 0) {
            while (__hip_atomic_load(&gcnt[(it - 1) * NW + w], __ATOMIC_ACQUIRE,
                                     __HIP_MEMORY_SCOPE_AGENT) < (unsigned)NBLK)
                __builtin_amdgcn_s_sleep(1);
            const size_t pbm = ((size_t)(it - 1) * NW + w) * NBLK;
            double Qt = 0.0, Rt = 0.0;
            #pragma unroll
            for (int i = 0; i < NBLK; ++i) {
                Qt += gpart[(pbm + i) * 2 + 0];
                Rt += gpart[(pbm + i) * 2 + 1];
            }
            if (it == 1)
                sxtot = sxbuf[w * NBLK + 0] + sxbuf[w * NBLK + 1] +
                        sxbuf[w * NBLK + 2] + sxbuf[w * NBLK + 3];
            const float loss = (float)((Qt + sxtot) / 32768.0 + 0.2 * (Rt / 8192.0));
            const float stat = fabsf(old_loss - loss) / old_loss;
            old_loss = loss;
            s_stop[p] = (stat < 1e-3f) ? 1 : 0;
        }

        __syncthreads();          // THE barrier: sp + s_stop[p] visible

        if (s_stop[p]) break;     // conv(it-1) gates update(it)

        // ---- K-reduce at owned coords ----
        float a4[4] = {0.f, 0.f, 0.f, 0.f};
        #pragma unroll
        for (int k2 = 0; k2 < 8; ++k2) {
            const float4 p4 = *(const float4*)&sp[xidx(k2, cgo, r)];
            a4[0] += p4.x; a4[1] += p4.y; a4[2] += p4.z; a4[3] += p4.w;
        }

        // ---- loss partials over owned coefs; last-man-out block post ----
        float qc = 0.f, rr = 0.f;
        #pragma unroll
        for (int j = 0; j < 4; ++j) {
            qc += cf[j] * (a4[j] - 2.f * xB[j]);
            rr += fabsf(cf[j]);
        }
        #pragma unroll
        for (int off = 32; off; off >>= 1) {
            qc += __shfl_down(qc, off);
            rr += __shfl_down(rr, off);
        }
        if (kg == 0) {
            s_redq[p][ks] = qc; s_redr[p][ks] = rr;
            __threadfence_block();     // s_red visible before the counter bump
            const unsigned old = __hip_atomic_fetch_add(&s_wcnt[p], 1u,
                                    __ATOMIC_ACQ_REL, __HIP_MEMORY_SCOPE_WORKGROUP);
            if (old == 7u) {           // last wave of the block: fixed-order sum + post
                float Q = 0.f, R = 0.f;
                #pragma unroll
                for (int i = 0; i < 8; ++i) { Q += s_redq[p][i]; R += s_redr[p][i]; }
                s_wcnt[p] = 0u;        // reuse at it+2 (ordered by barrier it+1)
                const size_t pb = ((size_t)it * NW + w) * NBLK;
                gpart[(pb + q) * 2 + 0] = (double)Q;
                gpart[(pb + q) * 2 + 1] = (double)R;
                __hip_atomic_fetch_add(&gcnt[it * NW + w], 1u,
                                       __ATOMIC_RELEASE, __HIP_MEMORY_SCOPE_AGENT);
            }
        }

        // ---- Adam update on owned coefs (registers only) ----
        b1p *= 0.9f; b2p *= 0.999f;
        const float bc1 = 1.f - b1p, bc2 = 1.f - b2p;
        #pragma unroll
        for (int j = 0; j < 4; ++j) {
            const float c_ = cf[j];
            const float sgn = (c_ > 0.f) ? 1.f : ((c_ < 0.f) ? -1.f : 0.f);
            const float gg = c1 * (a4[j] - xB[j]) + c2 * sgn;
            m_[j] = 0.9f * m_[j] + 0.1f * gg;
            v_[j] = 0.999f * v_[j] + 0.001f * gg * gg;
            cf[j] = c_ - 1e-3f * (m_[j] / bc1) / (sqrtf(v_[j] / bc2) + 1e-8f);
        }
    }

    // ---- out[b][k][w]: owned (row q*8+r, cols 4cgo..+3) ----
    #pragma unroll
    for (int j = 0; j < 4; ++j)
        out[((size_t)(q * RPB + r) * NB + 4 * cgo + j) * NW + w] = cf[j];
}

// ---------------------------------------------------------------------------
extern "C" void kernel_launch(void* const* d_in, const int* in_sizes, int n_in,
                              void* d_out, int out_size, void* d_ws, size_t ws_size,
                              hipStream_t stream)
{
    const float* spec   = (const float*)d_in[0];
    const float* basis  = (const float*)d_in[1];
    const int* p_niter  = (const int*)d_in[2];
    const int* p_pad    = (const int*)d_in[3];
    const int* p_stride = (const int*)d_in[4];
    float* out = (float*)d_out;

    char* ws = (char*)d_ws;
    float*        G     = (float*)ws;                         // 256 KB
    double*       sxbuf = (double*)(ws + 262144);             // 2016 B (pad 4 KB)
    double*       gpart = (double*)(ws + 266240);             // 193536 B
    unsigned int* gcnt  = (unsigned int*)(ws + 266240 + 193536); // (MAXIT*NW+1)*4

    hipMemsetAsync(gcnt, 0, (MAXIT * NW + 1) * sizeof(unsigned int), stream);
    window_kernel<<<dim3(GRID), dim3(512), 0, stream>>>(
        spec, basis, G, p_niter, p_pad, p_stride, sxbuf, gpart, gcnt, out);
}

// Round 10
// 312.062 us; speedup vs baseline: 2.9662x; 1.0342x over previous
//
#include <hip/hip_runtime.h>
#include <math.h>

// SparseCoding, round 10.
// vs R9 (323 us): cut per-iter coupling + instruction fat.
//  (1) LAG-2 convergence consume: iter it consumes totals of it-2 (~1.5 iters of
//      slack -> spin truly ~0, block decoupled from sibling jitter). Reference
//      semantics kept via cfp (prev-iter coef in regs): stop detected at it means
//      t*=it-2, answer = coef_{t*+1} = cfp. One post-loop consume round handles
//      conv at t=n_iter-2 (conv at n_iter-1 provably affects nothing).
//  (2) GEMM loop-swap (b outer): pacc[b] written to LDS as soon as complete ->
//      64 ds_write_b128 spread across GEMM VALU instead of bunched pre-barrier.
//      Same accumulation order (m ascending per pacc) -> bit-identical.
//  (3) Adam: precompute 1/bc1, 1/bc2 (saves ~6 div sequences/thread/iter).
#define NB     256
#define NF     128
#define FT     1024
#define NW     63
#define TORIG  256
#define MAXIT  48
#define RPB    8
#define NBLK   4
#define GRID   256           // XCD-swizzled; 4 blocks decode w==63: gram+exit

__device__ __forceinline__ float rl(float v, int lane) {
    return __uint_as_float((unsigned)__builtin_amdgcn_readlane((int)__float_as_uint(v), lane));
}

// exchange layout (float4 index): k2*512 + row*64 + (cg ^ row)
__device__ __forceinline__ int xidx(int k2, int cg, int row) {
    return (k2 * 512 + row * 64 + (cg ^ row)) * 4;
}

__global__ __launch_bounds__(512, 2) void window_kernel(
    const float* __restrict__ spec,
    const float* __restrict__ basis,
    float* __restrict__ G,               // ws: 256x256
    const int* __restrict__ p_niter,
    const int* __restrict__ p_pad,
    const int* __restrict__ p_stride,
    double* __restrict__ sxbuf,          // [NW][NBLK]
    double* __restrict__ gpart,          // [MAXIT][NW][NBLK][2]
    unsigned int* __restrict__ gcnt,     // [MAXIT*NW] arrivals + [MAXIT*NW]=gbar (memset 0)
    float* __restrict__ out)             // (32,256,63)
{
    __shared__ float  s_p0[RPB * 2048];        // 64 KB parity-0 exchange
    __shared__ float  s_p1[RPB * 2048];        // 64 KB parity-1; head doubles as s_xn
    __shared__ float  s_gred[2][NB];
    __shared__ float  s_mn[RPB], s_rng[RPB];
    __shared__ double s_dred[8];
    __shared__ float  s_redq[2][8], s_redr[2][8];
    __shared__ unsigned int s_wcnt[2];
    __shared__ int    s_stop[2];
    float* const s_xn = s_p1;                  // setup only

    const int bid = blockIdx.x;
    const int yy  = bid >> 3;
    const int q   = yy & 3;
    const int w   = (bid & 7) + 8 * (yy >> 2);   // 4 blocks/window share bid%8 (XCD)
    const int tid = threadIdx.x;
    const int ks  = tid >> 6;                    // wave: K-slice [32ks,32ks+32)
    const int kg  = tid & 63;
    const int r   = kg >> 3;                     // owned local row
    const int cgo = 8 * ks + (kg & 7);           // owned colgroup (cols 4cgo..4cgo+3)
    const int n_iter = p_niter[0];
    const int t0     = w * p_stride[0] - p_pad[0];
    unsigned int* gbar = gcnt + MAXIT * NW;

    // ================= fused Gram: block bid computes G row bid ==================
    {
        const int c = tid & 255, jh = tid >> 8;
        float acc = 0.f;
        const float* bp = basis + (size_t)(jh * 512) * NB;
        #pragma unroll 16
        for (int j = 0; j < 512; ++j)
            acc = fmaf(bp[j * NB + bid], bp[j * NB + c], acc);
        s_gred[jh][c] = acc;
        __syncthreads();
        if (jh == 0) G[(size_t)bid * NB + c] = s_gred[0][c] + s_gred[1][c];
    }
    __threadfence();
    __syncthreads();
    if (tid == 0) atomicAdd(gbar, 1u);
    if (w >= NW) return;

    // ================= stage raw window, min/max, normalize ======================
    #pragma unroll
    for (int i = 0; i < 16; ++i) {
        const int e = i * 512 + tid;
        const int b = e >> 10, jj = e & 1023;
        const int f = jj >> 3, t = jj & 7, tq = t0 + t;
        s_xn[b * FT + jj] = (tq >= 0 && tq < TORIG)
            ? spec[((size_t)(q * RPB + b) * NF + f) * TORIG + tq] : 0.f;
    }
    __syncthreads();
    {   // wave ks scans row ks
        float mn = __builtin_inff(), mx = -__builtin_inff();
        #pragma unroll
        for (int i = 0; i < 16; ++i) {
            const float v = s_xn[ks * FT + i * 64 + kg];
            mn = fminf(mn, v); mx = fmaxf(mx, v);
        }
        #pragma unroll
        for (int off = 32; off; off >>= 1) {
            mn = fminf(mn, __shfl_down(mn, off));
            mx = fmaxf(mx, __shfl_down(mx, off));
        }
        if (kg == 0) { s_mn[ks] = mn; s_rng[ks] = mx - mn; }
    }
    __syncthreads();
    double sx2p = 0.0;
    #pragma unroll
    for (int i = 0; i < 16; ++i) {
        const int e = i * 512 + tid;
        const int b = e >> 10, jj = e & 1023;
        const float v = (s_xn[b * FT + jj] - s_mn[b]) / s_rng[b];
        s_xn[b * FT + jj] = v;
        sx2p += (double)v * (double)v;
    }
    #pragma unroll
    for (int off = 32; off; off >>= 1) sx2p += __shfl_down(sx2p, off);
    if (kg == 0) s_dred[ks] = sx2p;
    __syncthreads();
    if (tid == 0) {
        double s = 0.0;
        #pragma unroll
        for (int i = 0; i < 8; ++i) s += s_dred[i];
        sxbuf[w * NBLK + q] = s;
        __threadfence();
    }

    // ================= xB = xnorm @ basis (K-split partials into s_p0) ===========
    float xbp[RPB][4];
    #pragma unroll
    for (int b = 0; b < RPB; ++b)
        #pragma unroll
        for (int j = 0; j < 4; ++j) xbp[b][j] = 0.f;
    for (int i0 = 0; i0 < 128; i0 += 4) {
        const int jj = ks * 128 + i0;
        float4 bv[4];
        #pragma unroll
        for (int t = 0; t < 4; ++t)
            bv[t] = *(const float4*)(basis + (size_t)(jj + t) * NB + 4 * kg);
        #pragma unroll
        for (int b = 0; b < RPB; ++b) {
            const float4 x4 = *(const float4*)&s_xn[b * FT + jj];
            xbp[b][0] = fmaf(x4.x, bv[0].x, fmaf(x4.y, bv[1].x, fmaf(x4.z, bv[2].x, fmaf(x4.w, bv[3].x, xbp[b][0]))));
            xbp[b][1] = fmaf(x4.x, bv[0].y, fmaf(x4.y, bv[1].y, fmaf(x4.z, bv[2].y, fmaf(x4.w, bv[3].y, xbp[b][1]))));
            xbp[b][2] = fmaf(x4.x, bv[0].z, fmaf(x4.y, bv[1].z, fmaf(x4.z, bv[2].z, fmaf(x4.w, bv[3].z, xbp[b][2]))));
            xbp[b][3] = fmaf(x4.x, bv[0].w, fmaf(x4.y, bv[1].w, fmaf(x4.z, bv[2].w, fmaf(x4.w, bv[3].w, xbp[b][3]))));
        }
    }
    __syncthreads();
    #pragma unroll
    for (int b = 0; b < RPB; ++b)
        *(float4*)&s_p0[xidx(ks, kg, b)] =
            make_float4(xbp[b][0], xbp[b][1], xbp[b][2], xbp[b][3]);
    __syncthreads();
    float xB[4] = {0.f, 0.f, 0.f, 0.f};
    #pragma unroll
    for (int k2 = 0; k2 < 8; ++k2) {
        const float4 p4 = *(const float4*)&s_p0[xidx(k2, cgo, r)];
        xB[0] += p4.x; xB[1] += p4.y; xB[2] += p4.z; xB[3] += p4.w;
    }

    // ================= wait for G, load register fragment ========================
    if (tid == 0) {
        while (__hip_atomic_load(gbar, __ATOMIC_ACQUIRE, __HIP_MEMORY_SCOPE_AGENT) < (unsigned)GRID)
            __builtin_amdgcn_s_sleep(1);
    }
    if (tid == 64) { s_wcnt[0] = 0; s_wcnt[1] = 0; s_stop[0] = 0; s_stop[1] = 0; }
    __syncthreads();
    float4 g[32];
    #pragma unroll
    for (int kl = 0; kl < 32; ++kl)
        g[kl] = *(const float4*)(G + (size_t)(32 * ks + kl) * NB + 4 * kg);

    // ================= init owned coef / Adam ====================================
    const float C0 = 0.5f / 256.f;
    float cf[4]  = {C0, C0, C0, C0}, cfp[4] = {C0, C0, C0, C0};
    float m_[4]  = {0, 0, 0, 0},    v_[4]  = {0, 0, 0, 0};
    float b1p = 1.f, b2p = 1.f;
    float old_loss = 1e-10f;      // tid64 only
    double sxtot = 0.0;           // tid64 only
    const float c1 = 2.f / 32768.f, c2 = 0.2f / 8192.f;
    int use_prev = 0;

    for (int it = 0; it < n_iter; ++it) {
        const int p = it & 1;
        float* const sp = p ? s_p1 : s_p0;

        // ---- tid64: LAG-2 consume (totals posted ~1.5 iterations ago) ----
        if (tid == 64 && it >= 2) {
            const int itc = it - 2;
            while (__hip_atomic_load(&gcnt[itc * NW + w], __ATOMIC_ACQUIRE,
                                     __HIP_MEMORY_SCOPE_AGENT) < (unsigned)NBLK)
                __builtin_amdgcn_s_sleep(1);
            const size_t pbm = ((size_t)itc * NW + w) * NBLK;
            double Qt = 0.0, Rt = 0.0;
            #pragma unroll
            for (int i = 0; i < NBLK; ++i) {
                Qt += gpart[(pbm + i) * 2 + 0];
                Rt += gpart[(pbm + i) * 2 + 1];
            }
            if (itc == 0)
                sxtot = sxbuf[w * NBLK + 0] + sxbuf[w * NBLK + 1] +
                        sxbuf[w * NBLK + 2] + sxbuf[w * NBLK + 3];
            const float loss = (float)((Qt + sxtot) / 32768.0 + 0.2 * (Rt / 8192.0));
            const float stat = fabsf(old_loss - loss) / old_loss;
            old_loss = loss;
            s_stop[p] = (stat < 1e-3f) ? 1 : 0;
        }

        // ---- GEMM, b outer: pacc[b] written to LDS as soon as complete ----
        #pragma unroll
        for (int b = 0; b < RPB; ++b) {
            float p0 = 0.f, p1 = 0.f, p2 = 0.f, p3 = 0.f;
            #pragma unroll
            for (int m = 0; m < 8; ++m) {
                const float4 ga = g[4 * m + 0], gb = g[4 * m + 1];
                const float4 gc = g[4 * m + 2], gd = g[4 * m + 3];
                const int L = b * 8 + m;     // lane owning coef[b][32ks+4m..+3]
                const float cx = rl(cf[0], L), cy = rl(cf[1], L);
                const float cz = rl(cf[2], L), cw = rl(cf[3], L);
                p0 = fmaf(cx, ga.x, fmaf(cy, gb.x, fmaf(cz, gc.x, fmaf(cw, gd.x, p0))));
                p1 = fmaf(cx, ga.y, fmaf(cy, gb.y, fmaf(cz, gc.y, fmaf(cw, gd.y, p1))));
                p2 = fmaf(cx, ga.z, fmaf(cy, gb.z, fmaf(cz, gc.z, fmaf(cw, gd.z, p2))));
                p3 = fmaf(cx, ga.w, fmaf(cy, gb.w, fmaf(cz, gc.w, fmaf(cw, gd.w, p3))));
            }
            *(float4*)&sp[xidx(ks, kg, b)] = make_float4(p0, p1, p2, p3);
        }

        __syncthreads();          // THE barrier: sp + s_stop[p] visible

        if (s_stop[p]) { use_prev = 1; break; }   // t*=it-2 -> answer = cfp

        // ---- K-reduce at owned coords ----
        float a4[4] = {0.f, 0.f, 0.f, 0.f};
        #pragma unroll
        for (int k2 = 0; k2 < 8; ++k2) {
            const float4 p4 = *(const float4*)&sp[xidx(k2, cgo, r)];
            a4[0] += p4.x; a4[1] += p4.y; a4[2] += p4.z; a4[3] += p4.w;
        }

        // ---- loss partials + last-man-out block post (skip on final iter) ----
        if (it + 1 < n_iter) {
            float qc = 0.f, rr = 0.f;
            #pragma unroll
            for (int j = 0; j < 4; ++j) {
                qc += cf[j] * (a4[j] - 2.f * xB[j]);
                rr += fabsf(cf[j]);
            }
            #pragma unroll
            for (int off = 32; off; off >>= 1) {
                qc += __shfl_down(qc, off);
                rr += __shfl_down(rr, off);
            }
            if (kg == 0) {
                s_redq[p][ks] = qc; s_redr[p][ks] = rr;
                __threadfence_block();
                const unsigned old = __hip_atomic_fetch_add(&s_wcnt[p], 1u,
                                        __ATOMIC_ACQ_REL, __HIP_MEMORY_SCOPE_WORKGROUP);
                if (old == 7u) {
                    float Q = 0.f, R = 0.f;
                    #pragma unroll
                    for (int i = 0; i < 8; ++i) { Q += s_redq[p][i]; R += s_redr[p][i]; }
                    s_wcnt[p] = 0u;
                    const size_t pb = ((size_t)it * NW + w) * NBLK;
                    gpart[(pb + q) * 2 + 0] = (double)Q;
                    gpart[(pb + q) * 2 + 1] = (double)R;
                    __hip_atomic_fetch_add(&gcnt[it * NW + w], 1u,
                                           __ATOMIC_RELEASE, __HIP_MEMORY_SCOPE_AGENT);
                }
            }
        }

        // ---- Adam update (cfp snapshot first; reciprocal bias correction) ----
        b1p *= 0.9f; b2p *= 0.999f;
        const float rb1 = 1.f / (1.f - b1p), rb2 = 1.f / (1.f - b2p);
        #pragma unroll
        for (int j = 0; j < 4; ++j) {
            const float c_ = cf[j];
            cfp[j] = c_;
            const float sgn = (c_ > 0.f) ? 1.f : ((c_ < 0.f) ? -1.f : 0.f);
            const float gg = c1 * (a4[j] - xB[j]) + c2 * sgn;
            m_[j] = 0.9f * m_[j] + 0.1f * gg;
            v_[j] = 0.999f * v_[j] + 0.001f * gg * gg;
            cf[j] = c_ - 1e-3f * (m_[j] * rb1) / (sqrtf(v_[j] * rb2) + 1e-8f);
        }
    }

    // ---- post-loop consume round: conv at t = n_iter-2 (if not already stopped) ----
    if (!use_prev && n_iter >= 2) {
        if (tid == 64) {
            const int itc = n_iter - 2;
            while (__hip_atomic_load(&gcnt[itc * NW + w], __ATOMIC_ACQUIRE,
                                     __HIP_MEMORY_SCOPE_AGENT) < (unsigned)NBLK)
                __builtin_amdgcn_s_sleep(1);
            const size_t pbm = ((size_t)itc * NW + w) * NBLK;
            double Qt = 0.0, Rt = 0.0;
            #pragma unroll
            for (int i = 0; i < NBLK; ++i) {
                Qt += gpart[(pbm + i) * 2 + 0];
                Rt += gpart[(pbm + i) * 2 + 1];
            }
            if (itc == 0)
                sxtot = sxbuf[w * NBLK + 0] + sxbuf[w * NBLK + 1] +
                        sxbuf[w * NBLK + 2] + sxbuf[w * NBLK + 3];
            const float loss = (float)((Qt + sxtot) / 32768.0 + 0.2 * (Rt / 8192.0));
            const float stat = fabsf(old_loss - loss) / old_loss;
            s_stop[0] = (stat < 1e-3f) ? 1 : 0;
        }
        __syncthreads();
        use_prev = s_stop[0];
    }

    // ---- out[b][k][w]: owned (row q*8+r, cols 4cgo..+3) ----
    #pragma unroll
    for (int j = 0; j < 4; ++j)
        out[((size_t)(q * RPB + r) * NB + 4 * cgo + j) * NW + w] =
            use_prev ? cfp[j] : cf[j];
}

// ---------------------------------------------------------------------------
extern "C" void kernel_launch(void* const* d_in, const int* in_sizes, int n_in,
                              void* d_out, int out_size, void* d_ws, size_t ws_size,
                              hipStream_t stream)
{
    const float* spec   = (const float*)d_in[0];
    const float* basis  = (const float*)d_in[1];
    const int* p_niter  = (const int*)d_in[2];
    const int* p_pad    = (const int*)d_in[3];
    const int* p_stride = (const int*)d_in[4];
    float* out = (float*)d_out;

    char* ws = (char*)d_ws;
    float*        G     = (float*)ws;                         // 256 KB
    double*       sxbuf = (double*)(ws + 262144);             // 2016 B (pad 4 KB)
    double*       gpart = (double*)(ws + 266240);             // 193536 B
    unsigned int* gcnt  = (unsigned int*)(ws + 266240 + 193536); // (MAXIT*NW+1)*4

    hipMemsetAsync(gcnt, 0, (MAXIT * NW + 1) * sizeof(unsigned int), stream);
    window_kernel<<<dim3(GRID), dim3(512), 0, stream>>>(
        spec, basis, G, p_niter, p_pad, p_stride, sxbuf, gpart, gcnt, out);
}